// Round 14
// baseline (690.956 us; speedup 1.0000x reference)
//
#include <hip/hip_runtime.h>
#include <hip/hip_bf16.h>

typedef __bf16 bf16;
typedef unsigned long long u64;
typedef __bf16 bf16x8 __attribute__((ext_vector_type(8)));
typedef __bf16 bf16x4 __attribute__((ext_vector_type(4)));
typedef float f32x4 __attribute__((ext_vector_type(4)));

#define NB 4
#define T 8192
#define C 128
#define NBLK 40
#define XS 136   // LDS row stride (bf16): 128 ch + 8 pad
#define NT 1024  // threads per WG (16 waves; 4 waves/SIMD at <=128 regs)

#define MFMA(a, b, c) __builtin_amdgcn_mfma_f32_16x16x32_bf16(a, b, c, 0, 0, 0)

__device__ __forceinline__ float bf2f(bf16 x){ return (float)x; }
__device__ __forceinline__ bf16 f2bf(float x){ return (bf16)x; }

__device__ __forceinline__ float ld(const void* p, int i, int isbf){
    return isbf ? bf2f(((const bf16*)p)[i]) : ((const float*)p)[i];
}

// Coherent 8B load (relaxed agent atomic -> bypasses stale L1/L2;
// compiler manages the waitcnt before use).
__device__ __forceinline__ bf16x4 ld8(const bf16* p){
    u64 v = __hip_atomic_load((const u64*)p, __ATOMIC_RELAXED, __HIP_MEMORY_SCOPE_AGENT);
    return __builtin_bit_cast(bf16x4, v);
}
// Coherent 16B store via asm (inputs only -> safe), caller drains vmcnt.
__device__ __forceinline__ void st16c(bf16* p, f32x4 v){
    asm volatile("global_store_dwordx4 %0, %1, off sc0 sc1" :: "v"(p), "v"(v) : "memory");
}

// Canonicalize inputs (8 elems per thread), dtype detect folded in (r12,
// proven): each block detects locally from x's first 128 u16; block 0
// publishes flag for k_main. SEPARATE KERNEL is mandatory: r13 showed
// in-kernel prep + plain cross-XCD reads hits stale non-coherent L2 (read
// poison); the kernel boundary provides the device-wide flush/invalidate.
// weff [40][256][256] bf16: weff[blk][o][c]=cw[blk][o][c][0] (t-d), [o][128+c]=cw[..][1] (t)
__global__ __launch_bounds__(256) void k_prep(
    const void* __restrict__ conv_w, const void* __restrict__ post_w,
    const void* __restrict__ lin1_w, const void* __restrict__ lin2_w,
    const void* __restrict__ x,      const void* __restrict__ conv_b,
    const void* __restrict__ post_b, const void* __restrict__ pre_w,
    const void* __restrict__ pre_b,  const void* __restrict__ lin1_b,
    const void* __restrict__ lin2_b,
    bf16* __restrict__ weff, bf16* __restrict__ pwc,
    bf16* __restrict__ w1c,  bf16* __restrict__ w2c,
    float* __restrict__ xc,  float* __restrict__ cbf,
    float* __restrict__ pbf, float* __restrict__ misc,
    int* __restrict__ flag){
    __shared__ int sf;
    if (threadIdx.x < 64){
        unsigned short v = ((const unsigned short*)x)[threadIdx.x * 2];
        int e = (v >> 7) & 255;
        bool sane = (e >= 100 && e <= 140) || ((v & 0x7FFF) == 0);
        unsigned long long m = __ballot(sane);
        if (threadIdx.x == 0){
            int fv = (__popcll(m) >= 48) ? 1 : 0;
            sf = fv;
            if (blockIdx.x == 0) *flag = fv;
        }
    }
    __syncthreads();
    int f = sf;
    int g = blockIdx.x * 256 + threadIdx.x;
    if (g < 327680){                 // weff: 40*256*256/8 granules
        int blk = g >> 13, r = g & 8191, o = r >> 5, j = r & 31;
        int k = (j >= 16) ? 1 : 0;
        int base = blk * 65536 + o * 256 + (j * 8 - k * 128) * 2 + k;
        bf16x8 v;
#pragma unroll
        for (int m = 0; m < 8; m++) v[m] = f2bf(ld(conv_w, base + m * 2, f));
        *(bf16x8*)(weff + (size_t)g * 8) = v;
    } else if (g < 409600){          // pwc
        int e = (g - 327680) * 8;
        bf16x8 v;
#pragma unroll
        for (int m = 0; m < 8; m++) v[m] = f2bf(ld(post_w, e + m, f));
        *(bf16x8*)(pwc + e) = v;
    } else if (g < 411648){          // w1c
        int e = (g - 409600) * 8;
        bf16x8 v;
#pragma unroll
        for (int m = 0; m < 8; m++) v[m] = f2bf(ld(lin1_w, e + m, f));
        *(bf16x8*)(w1c + e) = v;
    } else if (g < 413696){          // w2c
        int e = (g - 411648) * 8;
        bf16x8 v;
#pragma unroll
        for (int m = 0; m < 8; m++) v[m] = f2bf(ld(lin2_w, e + m, f));
        *(bf16x8*)(w2c + e) = v;
    } else if (g < 417792){          // xc (f32)
        int e = (g - 413696) * 8;
#pragma unroll
        for (int m = 0; m < 8; m++) xc[e + m] = ld(x, e + m, f);
    } else if (g < 419072){          // cbf
        int e = (g - 417792) * 8;
#pragma unroll
        for (int m = 0; m < 8; m++) cbf[e + m] = ld(conv_b, e + m, f);
    } else if (g < 419712){          // pbf
        int e = (g - 419072) * 8;
#pragma unroll
        for (int m = 0; m < 8; m++) pbf[e + m] = ld(post_b, e + m, f);
    } else if (g < 419808){          // misc
        int e = (g - 419712) * 8;
#pragma unroll
        for (int m = 0; m < 8; m++){
            int idx = e + m;
            if      (idx < 384) misc[idx] = ld(pre_w,  idx,       f);
            else if (idx < 512) misc[idx] = ld(pre_b,  idx - 384, f);
            else if (idx < 640) misc[idx] = ld(lin1_b, idx - 512, f);
            else                misc[idx] = ld(lin2_b, idx - 640, f);
        }
    }
}

__device__ __forceinline__ void wait_ge(unsigned* p, unsigned v){
    int guard = 0;
    while (__hip_atomic_load(p, __ATOMIC_RELAXED, __HIP_MEMORY_SCOPE_AGENT) < v){
        __builtin_amdgcn_s_sleep(1);
        if (++guard > (1 << 22)) break;   // failsafe against protocol bugs
    }
    asm volatile("" ::: "memory");
}

// Store tail rows [128-nrows, 128) of Xo to dst (global, coherent), then drain.
// 16B granules, 16 consecutive threads per row -> coalesced (round-9 lesson:
// scattered 8B register stores cost +80MB WRITE_SIZE and +58us).
__device__ __forceinline__ void tail_store(const bf16* Xo, bf16* dst, int nrows, int tid){
    int ngr = nrows * 16;                      // 16B granules
    for (int g = tid; g < ngr; g += NT){
        int rr = 128 - nrows + (g >> 4), co = (g & 15) * 8;
        f32x4 v = *(const f32x4*)(Xo + rr * XS + co);
        st16c(dst + (size_t)rr * C + co, v);
    }
    asm volatile("s_waitcnt vmcnt(0)" ::: "memory");
}

// Persistent kernel, 256 WGs x 1024 threads (16 waves), 1 WG/CU.
// Round-14: SAME algorithm/protocol/LDS as the proven 445.6us round-11 kernel;
// only the thread->work mapping changes. 16 waves halve per-thread state
// (hreg[16], ssum[16], cacc 2x4 AGPR) -> ~110 total regs/wave -> 4 waves/SIMD
// (vs 2), doubling latency hiding on the exposed weight-stream/staging/drain
// latencies that were ~60% of cycles. __launch_bounds__(1024,4) pins the
// allocator to <=128 regs. Wave wH=wv>>3 owns cols [wH*64, wH*64+64);
// wq=wv&7 owns ch rows [wq*16, wq*16+16) (same fragment mapping as before).
//   A: tap-t MFMA from Xo  ||  poll prog (all threads)
//   B: stage Xh rows [0, min(d,128)) from global (8B coherent)
//                                                 S1  (tid0 publishes cons)
//   C: tap-d MFMA, col>=d from Xo[col-d], col<d from Xh[col]
//   D: GLU -> S into Xs
//                                                 S2  (Xs visible)
//   E: post MFMA from Xs + residual -> Xo; anti-overwrite poll
//                                                 S3  (Xo visible)
//   F: tail_store 16B coalesced + drain
//                                                 S4  (stores drained)
//      tid0 publishes prog
// prog[w] = stages published (pre=1, layer i => i+2); cons[w] = staging reads done.
__global__ __launch_bounds__(1024, 4) void k_main(
    const float* __restrict__ xc,  const float* __restrict__ misc,
    const bf16* __restrict__ weff, const float* __restrict__ cbf,
    const bf16* __restrict__ pwc,  const float* __restrict__ pbf,
    const bf16* __restrict__ w1c,  const bf16* __restrict__ w2c,
    bf16* __restrict__ hA, bf16* __restrict__ hB,
    unsigned* __restrict__ prog, unsigned* __restrict__ cons,
    void* __restrict__ outv, const int* __restrict__ flag)
{
    // Single LDS array so phase C can use integer offsets off one base.
    __shared__ __align__(16) bf16 LDSB[3 * 128 * XS];   // 104,448 B
    bf16* Xo = LDSB;                 // own h^{(i)} tile
    bf16* Xh = LDSB + 128 * XS;      // staged remote rows
    bf16* Xs = LDSB + 256 * XS;      // skip S / Z / U

    int tid  = threadIdx.x;
    int wg   = blockIdx.x;             // 256
    int b    = wg >> 6;
    int slab = wg & 63;
    int t0   = slab * 128;
    int wv = tid >> 6, ln = tid & 63, lo = ln & 15, quad = ln >> 4;
    int wq = wv & 7, wH = wv >> 3;     // ch-group wave, col-half wave
    const int cb0 = wH * 64;           // this wave's column base
    const size_t hb = (size_t)b * T * C;

    float hreg[16];   // h[ch = wq*16+quad*4+r][col = cb0+ct*16+lo], idx ct*4+r
    float ssum[16];

    // ---- pre-net: hreg + Xo; tail-store 1 row (layer-0 d=1) ----
    {
        const float* xr = xc + b * T;
#pragma unroll
        for (int ct = 0; ct < 4; ct++){
            int col = cb0 + ct * 16 + lo;
            int t = t0 + col;
            float x0 = (t >= 2) ? xr[t - 2] : 0.f;
            float x1 = (t >= 1) ? xr[t - 1] : 0.f;
            float x2 = xr[t];
            bf16x4 hv;
#pragma unroll
            for (int r = 0; r < 4; r++){
                int c = wq * 16 + quad * 4 + r;
                float acc = misc[384 + c] + misc[c*3]*x0 + misc[c*3+1]*x1 + misc[c*3+2]*x2;
                hreg[ct * 4 + r] = acc;
                hv[r] = f2bf(acc);
            }
            *(bf16x4*)(Xo + col * XS + wq * 16 + quad * 4) = hv;
        }
    }
#pragma unroll
    for (int i = 0; i < 16; i++) ssum[i] = 0.f;
    __syncthreads();
    if (slab < 63) tail_store(Xo, hA + hb + (size_t)t0 * C, 1, tid);
    __syncthreads();
    if (tid == 0)
        __hip_atomic_store(prog + wg, 1u, __ATOMIC_RELAXED, __HIP_MEMORY_SCOPE_AGENT);

    // ---- 40 residual blocks ----
    for (int i = 0; i < NBLK; i++){
        int d  = 1 << (i % 10);
        int D  = (d >= 128) ? (d >> 7) : 1;
        int dn = (i < NBLK - 1) ? (1 << ((i + 1) % 10)) : 0;
        int Dn = (dn >= 128) ? (dn >> 7) : 1;
        int nst = (dn < 128) ? dn : 128;
        bool last = (i == NBLK - 1);
        bool do_store = !last && (slab + Dn <= 63);
        const bf16* hin  = (i & 1) ? hB : hA;
        bf16*       hout = (i & 1) ? hA : hB;
        const bf16* wb   = weff + ((size_t)i << 16);
        const bf16* pwb  = pwc  + i * 16384;
        const float* cb  = cbf + i * 256;
        const float* pb  = pbf + i * 128;

        f32x4 cacc0[4] = {}, cacc1[4] = {};

        // ---- phase A: tap-t MFMA from Xo (weights loaded once) ----
#pragma unroll
        for (int kk = 0; kk < 4; kk++){
            int ko = 128 + kk * 32 + quad * 8;
            bf16x8 a0 = *(const bf16x8*)(wb + (size_t)(wq*16 + lo) * 256 + ko);
            bf16x8 a1 = *(const bf16x8*)(wb + (size_t)(128 + wq*16 + lo) * 256 + ko);
#pragma unroll
            for (int ct = 0; ct < 4; ct++){
                bf16x8 bf_ = *(const bf16x8*)(Xo + (cb0 + ct*16 + lo) * XS + kk*32 + quad*8);
                cacc0[ct] = MFMA(a0, bf_, cacc0[ct]);
                cacc1[ct] = MFMA(a1, bf_, cacc1[ct]);
            }
        }
        // producer handshake: ALL threads poll
        if (slab >= D) wait_ge(prog + (wg - D), (unsigned)(i + 1));
        // ---- phase B: stage only remote rows [0, min(d,128)) from global ----
        {
            int nr = (d < 128) ? d : 128;
            int tbase = t0 - d;
            int ngr8 = nr * 32;
            for (int g = tid; g < ngr8; g += NT){
                int row = g >> 5, c4 = (g & 31) << 2;
                int t = tbase + row;
                bf16x4 v = {};
                if (t >= 0) v = ld8(hin + hb + (size_t)t * C + c4);
                *(bf16x4*)(Xh + row * XS + c4) = v;
            }
        }
        __syncthreads();                                   // S1: staging complete
        if (!last && tid == 0)
            __hip_atomic_store(cons + wg, (unsigned)(i + 1),
                               __ATOMIC_RELAXED, __HIP_MEMORY_SCOPE_AGENT);
        // ---- phase C: tap t-d MFMA; overlap cols read directly from Xo ----
        {
            int soff[4];
#pragma unroll
            for (int ct = 0; ct < 4; ct++){
                int col = cb0 + ct * 16 + lo;
                soff[ct] = (col >= d) ? (col - d) * XS            // Xo region
                                      : (128 * XS + col * XS);    // Xh region
            }
#pragma unroll
            for (int kk = 0; kk < 4; kk++){
                int ko = kk * 32 + quad * 8;
                bf16x8 a0 = *(const bf16x8*)(wb + (size_t)(wq*16 + lo) * 256 + ko);
                bf16x8 a1 = *(const bf16x8*)(wb + (size_t)(128 + wq*16 + lo) * 256 + ko);
#pragma unroll
                for (int ct = 0; ct < 4; ct++){
                    bf16x8 bf_ = *(const bf16x8*)(LDSB + soff[ct] + ko);
                    cacc0[ct] = MFMA(a0, bf_, cacc0[ct]);
                    cacc1[ct] = MFMA(a1, bf_, cacc1[ct]);
                }
            }
        }
        // ---- phase D: GLU -> S into Xs (no barrier needed after C) ----
#pragma unroll
        for (int ct = 0; ct < 4; ct++){
            int col = cb0 + ct * 16 + lo;
            bf16x4 sv;
#pragma unroll
            for (int r = 0; r < 4; r++){
                int j = wq * 16 + quad * 4 + r;
                float a = cacc0[ct][r] + cb[j];
                float g = cacc1[ct][r] + cb[128 + j];
                float s = a * __builtin_amdgcn_rcpf(1.f + __expf(-g));
                ssum[ct * 4 + r] += s;
                sv[r] = f2bf(s);
            }
            if (!last) *(bf16x4*)(Xs + col * XS + wq * 16 + quad * 4) = sv;
        }
        if (last) break;                                   // ssum complete
        __syncthreads();                                   // S2: Xs visible
        // ---- phase E: post MFMA + residual -> Xo ----
        {
            f32x4 pacc[4] = {};
#pragma unroll
            for (int kk = 0; kk < 4; kk++){
                bf16x8 pa = *(const bf16x8*)(pwb + (wq*16 + lo) * 128 + kk*32 + quad*8);
#pragma unroll
                for (int ct = 0; ct < 4; ct++){
                    bf16x8 pbv = *(const bf16x8*)(Xs + (cb0 + ct*16 + lo) * XS + kk*32 + quad*8);
                    pacc[ct] = MFMA(pa, pbv, pacc[ct]);
                }
            }
#pragma unroll
            for (int ct = 0; ct < 4; ct++){
                bf16x4 hv;
#pragma unroll
                for (int r = 0; r < 4; r++){
                    hreg[ct * 4 + r] += pacc[ct][r] + pb[wq * 16 + quad * 4 + r];
                    hv[r] = f2bf(hreg[ct * 4 + r]);
                }
                *(bf16x4*)(Xo + (cb0 + ct * 16 + lo) * XS + wq * 16 + quad * 4) = hv;
            }
        }
        // anti-overwrite: readers of h^{(i-1)} must be done (ALL threads poll)
        if (do_store && i >= 1){
            int dp = 1 << ((i - 1) % 10);
            int Dp = (dp >= 128) ? (dp >> 7) : 1;
            if (slab + Dp <= 63) wait_ge(cons + (wg + Dp), (unsigned)i);
        }
        __syncthreads();                                   // S3: Xo h^{(i+1)} visible
        // ---- phase F: coalesced tail store ----
        if (do_store) tail_store(Xo, hout + hb + (size_t)t0 * C, nst, tid);
        __syncthreads();                                   // S4: all stores drained
        if (tid == 0)
            __hip_atomic_store(prog + wg, (unsigned)(i + 2),
                               __ATOMIC_RELAXED, __HIP_MEMORY_SCOPE_AGENT);
    }

    // ---- final: relu(ssum) -> lin1 -> relu -> lin2 -> out [T][B][C] ----
    const float* b1 = misc + 512;
    const float* b2 = misc + 640;
    int isbf = *flag;
    __syncthreads();          // seal last layer's LDS reads before reuse
#pragma unroll
    for (int ct = 0; ct < 4; ct++){
        int col = cb0 + ct * 16 + lo;
        bf16x4 zv;
#pragma unroll
        for (int r = 0; r < 4; r++){
            float z = ssum[ct * 4 + r];
            zv[r] = f2bf(z > 0.f ? z : 0.f);
        }
        *(bf16x4*)(Xs + col * XS + wq * 16 + quad * 4) = zv;
    }
    __syncthreads();
    f32x4 a1[4] = {};
#pragma unroll
    for (int kk = 0; kk < 4; kk++){
        bf16x8 pa = *(const bf16x8*)(w1c + (wq*16 + lo) * 128 + kk*32 + quad*8);
#pragma unroll
        for (int ct = 0; ct < 4; ct++){
            bf16x8 pbv = *(const bf16x8*)(Xs + (cb0 + ct*16 + lo) * XS + kk*32 + quad*8);
            a1[ct] = MFMA(pa, pbv, a1[ct]);
        }
    }
    __syncthreads();
#pragma unroll
    for (int ct = 0; ct < 4; ct++){
        int col = cb0 + ct * 16 + lo;
        bf16x4 uv;
#pragma unroll
        for (int r = 0; r < 4; r++){
            int row = wq * 16 + quad * 4 + r;
            float u = a1[ct][r] + b1[row];
            uv[r] = f2bf(u > 0.f ? u : 0.f);
        }
        *(bf16x4*)(Xs + col * XS + wq * 16 + quad * 4) = uv;
    }
    __syncthreads();
    f32x4 a2[4] = {};
#pragma unroll
    for (int kk = 0; kk < 4; kk++){
        bf16x8 pa = *(const bf16x8*)(w2c + (wq*16 + lo) * 128 + kk*32 + quad*8);
#pragma unroll
        for (int ct = 0; ct < 4; ct++){
            bf16x8 pbv = *(const bf16x8*)(Xs + (cb0 + ct*16 + lo) * XS + kk*32 + quad*8);
            a2[ct] = MFMA(pa, pbv, a2[ct]);
        }
    }
#pragma unroll
    for (int ct = 0; ct < 4; ct++){
        int col = t0 + cb0 + ct * 16 + lo;
#pragma unroll
        for (int r = 0; r < 4; r++){
            int row = wq * 16 + quad * 4 + r;
            float v = a2[ct][r] + b2[row];
            size_t oi = ((size_t)col * NB + b) * C + row;
            if (isbf) ((bf16*)outv)[oi] = f2bf(v);
            else      ((float*)outv)[oi] = v;
        }
    }
}

extern "C" void kernel_launch(void* const* d_in, const int* in_sizes, int n_in,
                              void* d_out, int out_size, void* d_ws, size_t ws_size,
                              hipStream_t stream){
    const void* x      = d_in[0];
    const void* pre_w  = d_in[1];
    const void* pre_b  = d_in[2];
    const void* conv_w = d_in[3];
    const void* conv_b = d_in[4];
    const void* post_w = d_in[5];
    const void* post_b = d_in[6];
    const void* lin1w  = d_in[7];
    const void* lin1b  = d_in[8];
    const void* lin2w  = d_in[9];
    const void* lin2b  = d_in[10];

    char* ws = (char*)d_ws;
    bf16*     hA   = (bf16*)    (ws);                   //  8,388,608 B
    bf16*     hB   = (bf16*)    (ws +  8388608);        //  8,388,608 B
    bf16*     weff = (bf16*)    (ws + 16777216);        //  5,242,880 B
    bf16*     pwc  = (bf16*)    (ws + 22020096);        //  1,310,720 B
    bf16*     w1c  = (bf16*)    (ws + 23330816);        //     32,768 B
    bf16*     w2c  = (bf16*)    (ws + 23363584);        //     32,768 B
    float*    xc   = (float*)   (ws + 23396352);        //    131,072 B
    float*    cbf  = (float*)   (ws + 23527424);        //     40,960 B
    float*    pbf  = (float*)   (ws + 23568384);        //     20,480 B
    float*    misc = (float*)   (ws + 23588864);        //      3,072 B
    int*      flag = (int*)     (ws + 23591936);        //          4 B
    unsigned* prog = (unsigned*)(ws + 23592960);        //      1,024 B
    unsigned* cons = (unsigned*)(ws + 23593984);        //      1,024 B

    hipMemsetAsync(prog, 0, 2048, stream);
    k_prep<<<1640, 256, 0, stream>>>(conv_w, post_w, lin1w, lin2w, x, conv_b,
                                     post_b, pre_w, pre_b, lin1b, lin2b,
                                     weff, pwc, w1c, w2c, xc, cbf, pbf, misc, flag);

    const float* xc_c   = xc;   const float* misc_c = misc;
    const bf16*  weff_c = weff; const float* cbf_c  = cbf;
    const bf16*  pwc_c  = pwc;  const float* pbf_c  = pbf;
    const bf16*  w1c_c  = w1c;  const bf16*  w2c_c  = w2c;
    void* out_v = d_out;        const int* flag_c = flag;
    void* ka[14] = { &xc_c, &misc_c, &weff_c, &cbf_c, &pwc_c, &pbf_c,
                     &w1c_c, &w2c_c, &hA, &hB, &prog, &cons, &out_v, &flag_c };
    hipLaunchCooperativeKernel((void*)k_main, dim3(256), dim3(1024), ka, 0, stream);
}

// Round 15
// 536.251 us; speedup vs baseline: 1.2885x; 1.2885x over previous
//
#include <hip/hip_runtime.h>
#include <hip/hip_bf16.h>

typedef __bf16 bf16;
typedef unsigned long long u64;
typedef __bf16 bf16x8 __attribute__((ext_vector_type(8)));
typedef __bf16 bf16x4 __attribute__((ext_vector_type(4)));
typedef float f32x4 __attribute__((ext_vector_type(4)));

#define NB 4
#define T 8192
#define C 128
#define NBLK 40
#define XS 136   // LDS row stride (bf16): 128 ch + 8 pad

#define MFMA(a, b, c) __builtin_amdgcn_mfma_f32_16x16x32_bf16(a, b, c, 0, 0, 0)

__device__ __forceinline__ float bf2f(bf16 x){ return (float)x; }
__device__ __forceinline__ bf16 f2bf(float x){ return (bf16)x; }

__device__ __forceinline__ float ld(const void* p, int i, int isbf){
    return isbf ? bf2f(((const bf16*)p)[i]) : ((const float*)p)[i];
}

// Coherent 8B load (relaxed agent atomic -> bypasses stale L1/L2;
// compiler manages the waitcnt before use).
__device__ __forceinline__ bf16x4 ld8(const bf16* p){
    u64 v = __hip_atomic_load((const u64*)p, __ATOMIC_RELAXED, __HIP_MEMORY_SCOPE_AGENT);
    return __builtin_bit_cast(bf16x4, v);
}
// Coherent 16B store via asm (inputs only -> safe), caller drains vmcnt.
__device__ __forceinline__ void st16c(bf16* p, f32x4 v){
    asm volatile("global_store_dwordx4 %0, %1, off sc0 sc1" :: "v"(p), "v"(v) : "memory");
}

// Canonicalize inputs (8 elems per thread), dtype detect folded in (proven
// r12 form). SEPARATE KERNEL is mandatory: r13 showed in-kernel prep + plain
// cross-XCD reads hits stale non-coherent L2; the kernel boundary provides
// the device-wide flush/invalidate.
// weff [40][256][256] bf16: weff[blk][o][c]=cw[blk][o][c][0] (t-d), [o][128+c]=cw[..][1] (t)
__global__ __launch_bounds__(256) void k_prep(
    const void* __restrict__ conv_w, const void* __restrict__ post_w,
    const void* __restrict__ lin1_w, const void* __restrict__ lin2_w,
    const void* __restrict__ x,      const void* __restrict__ conv_b,
    const void* __restrict__ post_b, const void* __restrict__ pre_w,
    const void* __restrict__ pre_b,  const void* __restrict__ lin1_b,
    const void* __restrict__ lin2_b,
    bf16* __restrict__ weff, bf16* __restrict__ pwc,
    bf16* __restrict__ w1c,  bf16* __restrict__ w2c,
    float* __restrict__ xc,  float* __restrict__ cbf,
    float* __restrict__ pbf, float* __restrict__ misc,
    int* __restrict__ flag){
    __shared__ int sf;
    if (threadIdx.x < 64){
        unsigned short v = ((const unsigned short*)x)[threadIdx.x * 2];
        int e = (v >> 7) & 255;
        bool sane = (e >= 100 && e <= 140) || ((v & 0x7FFF) == 0);
        unsigned long long m = __ballot(sane);
        if (threadIdx.x == 0){
            int fv = (__popcll(m) >= 48) ? 1 : 0;
            sf = fv;
            if (blockIdx.x == 0) *flag = fv;
        }
    }
    __syncthreads();
    int f = sf;
    int g = blockIdx.x * 256 + threadIdx.x;
    if (g < 327680){                 // weff: 40*256*256/8 granules
        int blk = g >> 13, r = g & 8191, o = r >> 5, j = r & 31;
        int k = (j >= 16) ? 1 : 0;
        int base = blk * 65536 + o * 256 + (j * 8 - k * 128) * 2 + k;
        bf16x8 v;
#pragma unroll
        for (int m = 0; m < 8; m++) v[m] = f2bf(ld(conv_w, base + m * 2, f));
        *(bf16x8*)(weff + (size_t)g * 8) = v;
    } else if (g < 409600){          // pwc
        int e = (g - 327680) * 8;
        bf16x8 v;
#pragma unroll
        for (int m = 0; m < 8; m++) v[m] = f2bf(ld(post_w, e + m, f));
        *(bf16x8*)(pwc + e) = v;
    } else if (g < 411648){          // w1c
        int e = (g - 409600) * 8;
        bf16x8 v;
#pragma unroll
        for (int m = 0; m < 8; m++) v[m] = f2bf(ld(lin1_w, e + m, f));
        *(bf16x8*)(w1c + e) = v;
    } else if (g < 413696){          // w2c
        int e = (g - 411648) * 8;
        bf16x8 v;
#pragma unroll
        for (int m = 0; m < 8; m++) v[m] = f2bf(ld(lin2_w, e + m, f));
        *(bf16x8*)(w2c + e) = v;
    } else if (g < 417792){          // xc (f32)
        int e = (g - 413696) * 8;
#pragma unroll
        for (int m = 0; m < 8; m++) xc[e + m] = ld(x, e + m, f);
    } else if (g < 419072){          // cbf
        int e = (g - 417792) * 8;
#pragma unroll
        for (int m = 0; m < 8; m++) cbf[e + m] = ld(conv_b, e + m, f);
    } else if (g < 419712){          // pbf
        int e = (g - 419072) * 8;
#pragma unroll
        for (int m = 0; m < 8; m++) pbf[e + m] = ld(post_b, e + m, f);
    } else if (g < 419808){          // misc
        int e = (g - 419712) * 8;
#pragma unroll
        for (int m = 0; m < 8; m++){
            int idx = e + m;
            if      (idx < 384) misc[idx] = ld(pre_w,  idx,       f);
            else if (idx < 512) misc[idx] = ld(pre_b,  idx - 384, f);
            else if (idx < 640) misc[idx] = ld(lin1_b, idx - 512, f);
            else                misc[idx] = ld(lin2_b, idx - 640, f);
        }
    }
}

__device__ __forceinline__ void wait_ge(unsigned* p, unsigned v){
    int guard = 0;
    while (__hip_atomic_load(p, __ATOMIC_RELAXED, __HIP_MEMORY_SCOPE_AGENT) < v){
        __builtin_amdgcn_s_sleep(1);
        if (++guard > (1 << 22)) break;   // failsafe against protocol bugs
    }
    asm volatile("" ::: "memory");
}

// Store tail rows [128-nrows, 128) of Xo to dst (global, coherent), then drain.
// 16B granules, 16 consecutive threads per row -> coalesced (round-9 lesson:
// scattered 8B register stores cost +80MB WRITE_SIZE and +58us).
__device__ __forceinline__ void tail_store(const bf16* Xo, bf16* dst, int nrows, int tid){
    int ngr = nrows * 16;                      // 16B granules
    for (int g = tid; g < ngr; g += 512){
        int rr = 128 - nrows + (g >> 4), co = (g & 15) * 8;
        f32x4 v = *(const f32x4*)(Xo + rr * XS + co);
        st16c(dst + (size_t)rr * C + co, v);
    }
    asm volatile("s_waitcnt vmcnt(0)" ::: "memory");
}

// Persistent kernel, 256 WGs x 512 threads, 1 WG/CU — FINAL proven structure
// (round-11, 445.6us steady / 540us total). Experiments that FAILED against
// this floor (do not retry): register prefetch across MFMA (r12: spills at
// the ~128-reg ceiling), in-kernel prep (r13: cross-XCD L2 non-coherence),
// 16-wave occupancy (r14: barrier-lockstep -> TLP can't hide phase-end
// latency; weight loads duplicated; launch_bounds spills). The per-layer
// serial chain (weight-stream startup + coherent staging + drains) is the
// structural floor of this 40-deep cross-slab dependency.
//   A: tap-t MFMA from Xo (no deps)  ||  poll prog (all threads)
//   B: stage Xh rows [0, min(d,128)) from global (8B coherent)
//                                                 S1  (tid0 publishes cons)
//   C: tap-d MFMA, row>=d from Xo[row-d], row<d from Xh[row]
//   D: GLU -> S into Xs  (third buffer: no WAR vs C's reads -> no barrier C->D)
//                                                 S2  (Xs visible)
//   E: post MFMA from Xs + residual -> Xo; anti-overwrite poll
//                                                 S3  (Xo visible)
//   F: tail_store 16B coalesced + drain
//                                                 S4  (stores drained)
//      tid0 publishes prog
// prog[w] = stages published (pre=1, layer i => i+2); cons[w] = staging reads done.
__global__ __launch_bounds__(512, 2) void k_main(
    const float* __restrict__ xc,  const float* __restrict__ misc,
    const bf16* __restrict__ weff, const float* __restrict__ cbf,
    const bf16* __restrict__ pwc,  const float* __restrict__ pbf,
    const bf16* __restrict__ w1c,  const bf16* __restrict__ w2c,
    bf16* __restrict__ hA, bf16* __restrict__ hB,
    unsigned* __restrict__ prog, unsigned* __restrict__ cons,
    void* __restrict__ outv, const int* __restrict__ flag)
{
    // Single LDS array so phase C can use integer offsets off one base.
    __shared__ __align__(16) bf16 LDSB[3 * 128 * XS];   // 104,448 B
    bf16* Xo = LDSB;                 // own h^{(i)} tile
    bf16* Xh = LDSB + 128 * XS;      // staged remote rows
    bf16* Xs = LDSB + 256 * XS;      // skip S / Z / U

    int tid  = threadIdx.x;
    int wg   = blockIdx.x;             // 256
    int b    = wg >> 6;
    int slab = wg & 63;
    int t0   = slab * 128;
    int wv = tid >> 6, ln = tid & 63, lo = ln & 15, quad = ln >> 4;
    const size_t hb = (size_t)b * T * C;

    float hreg[32];   // h[c = wv*16+quad*4+r][t = t0+ct*16+lo], idx ct*4+r (ct 0..7)
    float ssum[32];

    // ---- pre-net: hreg + Xo; tail-store 1 row (layer-0 d=1) ----
    {
        const float* xr = xc + b * T;
#pragma unroll
        for (int ct = 0; ct < 8; ct++){
            int t = t0 + ct * 16 + lo;
            float x0 = (t >= 2) ? xr[t - 2] : 0.f;
            float x1 = (t >= 1) ? xr[t - 1] : 0.f;
            float x2 = xr[t];
            bf16x4 hv;
#pragma unroll
            for (int r = 0; r < 4; r++){
                int c = wv * 16 + quad * 4 + r;
                float acc = misc[384 + c] + misc[c*3]*x0 + misc[c*3+1]*x1 + misc[c*3+2]*x2;
                hreg[ct * 4 + r] = acc;
                hv[r] = f2bf(acc);
            }
            *(bf16x4*)(Xo + (ct * 16 + lo) * XS + wv * 16 + quad * 4) = hv;
        }
    }
#pragma unroll
    for (int i = 0; i < 32; i++) ssum[i] = 0.f;
    __syncthreads();
    if (slab < 63) tail_store(Xo, hA + hb + (size_t)t0 * C, 1, tid);
    __syncthreads();
    if (tid == 0)
        __hip_atomic_store(prog + wg, 1u, __ATOMIC_RELAXED, __HIP_MEMORY_SCOPE_AGENT);

    // ---- 40 residual blocks ----
    for (int i = 0; i < NBLK; i++){
        int d  = 1 << (i % 10);
        int D  = (d >= 128) ? (d >> 7) : 1;
        int dn = (i < NBLK - 1) ? (1 << ((i + 1) % 10)) : 0;
        int Dn = (dn >= 128) ? (dn >> 7) : 1;
        int nst = (dn < 128) ? dn : 128;
        bool last = (i == NBLK - 1);
        bool do_store = !last && (slab + Dn <= 63);
        const bf16* hin  = (i & 1) ? hB : hA;
        bf16*       hout = (i & 1) ? hA : hB;
        const bf16* wb   = weff + ((size_t)i << 16);
        const bf16* pwb  = pwc  + i * 16384;
        const float* cb  = cbf + i * 256;
        const float* pb  = pbf + i * 128;

        f32x4 cacc0[8] = {}, cacc1[8] = {};

        // ---- phase A: tap-t MFMA from Xo (weights loaded once) ----
#pragma unroll
        for (int kk = 0; kk < 4; kk++){
            int ko = 128 + kk * 32 + quad * 8;
            bf16x8 a0 = *(const bf16x8*)(wb + (size_t)(wv*16 + lo) * 256 + ko);
            bf16x8 a1 = *(const bf16x8*)(wb + (size_t)(128 + wv*16 + lo) * 256 + ko);
#pragma unroll
            for (int ct = 0; ct < 8; ct++){
                bf16x8 bf_ = *(const bf16x8*)(Xo + (ct*16 + lo) * XS + kk*32 + quad*8);
                cacc0[ct] = MFMA(a0, bf_, cacc0[ct]);
                cacc1[ct] = MFMA(a1, bf_, cacc1[ct]);
            }
        }
        // producer handshake: ALL threads poll
        if (slab >= D) wait_ge(prog + (wg - D), (unsigned)(i + 1));
        // ---- phase B: stage only remote rows [0, min(d,128)) from global ----
        {
            int nr = (d < 128) ? d : 128;
            int tbase = t0 - d;
            int ngr8 = nr * 32;
            for (int g = tid; g < ngr8; g += 512){
                int row = g >> 5, c4 = (g & 31) << 2;
                int t = tbase + row;
                bf16x4 v = {};
                if (t >= 0) v = ld8(hin + hb + (size_t)t * C + c4);
                *(bf16x4*)(Xh + row * XS + c4) = v;
            }
        }
        __syncthreads();                                   // S1: staging complete
        if (!last && tid == 0)
            __hip_atomic_store(cons + wg, (unsigned)(i + 1),
                               __ATOMIC_RELAXED, __HIP_MEMORY_SCOPE_AGENT);
        // ---- phase C: tap t-d MFMA; overlap rows read directly from Xo ----
        {
            int soff[8];
#pragma unroll
            for (int ct = 0; ct < 8; ct++){
                int row = ct * 16 + lo;
                soff[ct] = (row >= d) ? (row - d) * XS            // Xo region
                                      : (128 * XS + row * XS);    // Xh region
            }
#pragma unroll
            for (int kk = 0; kk < 4; kk++){
                int ko = kk * 32 + quad * 8;
                bf16x8 a0 = *(const bf16x8*)(wb + (size_t)(wv*16 + lo) * 256 + ko);
                bf16x8 a1 = *(const bf16x8*)(wb + (size_t)(128 + wv*16 + lo) * 256 + ko);
#pragma unroll
                for (int ct = 0; ct < 8; ct++){
                    bf16x8 bf_ = *(const bf16x8*)(LDSB + soff[ct] + ko);
                    cacc0[ct] = MFMA(a0, bf_, cacc0[ct]);
                    cacc1[ct] = MFMA(a1, bf_, cacc1[ct]);
                }
            }
        }
        // ---- phase D: GLU -> S into Xs (no barrier needed after C) ----
#pragma unroll
        for (int ct = 0; ct < 8; ct++){
            int col = ct * 16 + lo;
            bf16x4 sv;
#pragma unroll
            for (int r = 0; r < 4; r++){
                int j = wv * 16 + quad * 4 + r;
                float a = cacc0[ct][r] + cb[j];
                float g = cacc1[ct][r] + cb[128 + j];
                float s = a * __builtin_amdgcn_rcpf(1.f + __expf(-g));
                ssum[ct * 4 + r] += s;
                sv[r] = f2bf(s);
            }
            if (!last) *(bf16x4*)(Xs + col * XS + wv * 16 + quad * 4) = sv;
        }
        if (last) break;                                   // ssum complete
        __syncthreads();                                   // S2: Xs visible
        // ---- phase E: post MFMA + residual -> Xo ----
        {
            f32x4 pacc[8] = {};
#pragma unroll
            for (int kk = 0; kk < 4; kk++){
                bf16x8 pa = *(const bf16x8*)(pwb + (wv*16 + lo) * 128 + kk*32 + quad*8);
#pragma unroll
                for (int ct = 0; ct < 8; ct++){
                    bf16x8 pbv = *(const bf16x8*)(Xs + (ct*16 + lo) * XS + kk*32 + quad*8);
                    pacc[ct] = MFMA(pa, pbv, pacc[ct]);
                }
            }
#pragma unroll
            for (int ct = 0; ct < 8; ct++){
                bf16x4 hv;
#pragma unroll
                for (int r = 0; r < 4; r++){
                    hreg[ct * 4 + r] += pacc[ct][r] + pb[wv * 16 + quad * 4 + r];
                    hv[r] = f2bf(hreg[ct * 4 + r]);
                }
                *(bf16x4*)(Xo + (ct * 16 + lo) * XS + wv * 16 + quad * 4) = hv;
            }
        }
        // anti-overwrite: readers of h^{(i-1)} must be done (ALL threads poll)
        if (do_store && i >= 1){
            int dp = 1 << ((i - 1) % 10);
            int Dp = (dp >= 128) ? (dp >> 7) : 1;
            if (slab + Dp <= 63) wait_ge(cons + (wg + Dp), (unsigned)i);
        }
        __syncthreads();                                   // S3: Xo h^{(i+1)} visible
        // ---- phase F: coalesced tail store ----
        if (do_store) tail_store(Xo, hout + hb + (size_t)t0 * C, nst, tid);
        __syncthreads();                                   // S4: all stores drained
        if (tid == 0)
            __hip_atomic_store(prog + wg, (unsigned)(i + 2),
                               __ATOMIC_RELAXED, __HIP_MEMORY_SCOPE_AGENT);
    }

    // ---- final: relu(ssum) -> lin1 -> relu -> lin2 -> out [T][B][C] ----
    const float* b1 = misc + 512;
    const float* b2 = misc + 640;
    int isbf = *flag;
    __syncthreads();          // seal last layer's LDS reads before reuse
#pragma unroll
    for (int ct = 0; ct < 8; ct++){
        int col = ct * 16 + lo;
        bf16x4 zv;
#pragma unroll
        for (int r = 0; r < 4; r++){
            float z = ssum[ct * 4 + r];
            zv[r] = f2bf(z > 0.f ? z : 0.f);
        }
        *(bf16x4*)(Xs + col * XS + wv * 16 + quad * 4) = zv;
    }
    __syncthreads();
    f32x4 a1[8] = {};
#pragma unroll
    for (int kk = 0; kk < 4; kk++){
        bf16x8 pa = *(const bf16x8*)(w1c + (wv*16 + lo) * 128 + kk*32 + quad*8);
#pragma unroll
        for (int ct = 0; ct < 8; ct++){
            bf16x8 pbv = *(const bf16x8*)(Xs + (ct*16 + lo) * XS + kk*32 + quad*8);
            a1[ct] = MFMA(pa, pbv, a1[ct]);
        }
    }
    __syncthreads();
#pragma unroll
    for (int ct = 0; ct < 8; ct++){
        int col = ct * 16 + lo;
        bf16x4 uv;
#pragma unroll
        for (int r = 0; r < 4; r++){
            int row = wv * 16 + quad * 4 + r;
            float u = a1[ct][r] + b1[row];
            uv[r] = f2bf(u > 0.f ? u : 0.f);
        }
        *(bf16x4*)(Xs + col * XS + wv * 16 + quad * 4) = uv;
    }
    __syncthreads();
    f32x4 a2[8] = {};
#pragma unroll
    for (int kk = 0; kk < 4; kk++){
        bf16x8 pa = *(const bf16x8*)(w2c + (wv*16 + lo) * 128 + kk*32 + quad*8);
#pragma unroll
        for (int ct = 0; ct < 8; ct++){
            bf16x8 pbv = *(const bf16x8*)(Xs + (ct*16 + lo) * XS + kk*32 + quad*8);
            a2[ct] = MFMA(pa, pbv, a2[ct]);
        }
    }
#pragma unroll
    for (int ct = 0; ct < 8; ct++){
        int col = t0 + ct * 16 + lo;
#pragma unroll
        for (int r = 0; r < 4; r++){
            int row = wv * 16 + quad * 4 + r;
            float v = a2[ct][r] + b2[row];
            size_t oi = ((size_t)col * NB + b) * C + row;
            if (isbf) ((bf16*)outv)[oi] = f2bf(v);
            else      ((float*)outv)[oi] = v;
        }
    }
}

extern "C" void kernel_launch(void* const* d_in, const int* in_sizes, int n_in,
                              void* d_out, int out_size, void* d_ws, size_t ws_size,
                              hipStream_t stream){
    const void* x      = d_in[0];
    const void* pre_w  = d_in[1];
    const void* pre_b  = d_in[2];
    const void* conv_w = d_in[3];
    const void* conv_b = d_in[4];
    const void* post_w = d_in[5];
    const void* post_b = d_in[6];
    const void* lin1w  = d_in[7];
    const void* lin1b  = d_in[8];
    const void* lin2w  = d_in[9];
    const void* lin2b  = d_in[10];

    char* ws = (char*)d_ws;
    bf16*     hA   = (bf16*)    (ws);                   //  8,388,608 B
    bf16*     hB   = (bf16*)    (ws +  8388608);        //  8,388,608 B
    bf16*     weff = (bf16*)    (ws + 16777216);        //  5,242,880 B
    bf16*     pwc  = (bf16*)    (ws + 22020096);        //  1,310,720 B
    bf16*     w1c  = (bf16*)    (ws + 23330816);        //     32,768 B
    bf16*     w2c  = (bf16*)    (ws + 23363584);        //     32,768 B
    float*    xc   = (float*)   (ws + 23396352);        //    131,072 B
    float*    cbf  = (float*)   (ws + 23527424);        //     40,960 B
    float*    pbf  = (float*)   (ws + 23568384);        //     20,480 B
    float*    misc = (float*)   (ws + 23588864);        //      3,072 B
    int*      flag = (int*)     (ws + 23591936);        //          4 B
    unsigned* prog = (unsigned*)(ws + 23592960);        //      1,024 B
    unsigned* cons = (unsigned*)(ws + 23593984);        //      1,024 B

    hipMemsetAsync(prog, 0, 2048, stream);
    k_prep<<<1640, 256, 0, stream>>>(conv_w, post_w, lin1w, lin2w, x, conv_b,
                                     post_b, pre_w, pre_b, lin1b, lin2b,
                                     weff, pwc, w1c, w2c, xc, cbf, pbf, misc, flag);

    const float* xc_c   = xc;   const float* misc_c = misc;
    const bf16*  weff_c = weff; const float* cbf_c  = cbf;
    const bf16*  pwc_c  = pwc;  const float* pbf_c  = pbf;
    const bf16*  w1c_c  = w1c;  const bf16*  w2c_c  = w2c;
    void* out_v = d_out;        const int* flag_c = flag;
    void* ka[14] = { &xc_c, &misc_c, &weff_c, &cbf_c, &pwc_c, &pbf_c,
                     &w1c_c, &w2c_c, &hA, &hB, &prog, &cons, &out_v, &flag_c };
    hipLaunchCooperativeKernel((void*)k_main, dim3(256), dim3(512), ka, 0, stream);
}